// Round 14
// baseline (3988.004 us; speedup 1.0000x reference)
//
#include <hip/hip_runtime.h>
#include <stdint.h>
#include <stddef.h>

#define TT 1024
#define BB 64
#define HH 1024
#define II 1024

typedef __attribute__((ext_vector_type(8))) short s16x8;
typedef __attribute__((ext_vector_type(4))) float f32x4;
typedef __attribute__((ext_vector_type(2))) unsigned u32x2;

// ---- workspace layout (bytes) ---- (proven footprint, <= 266240)
// 512  : flags[8][64] u32 (per group 256 B; words 0..7 used = 8 blocks)
// 4096 : ring: group*32768 + slot*16384 + row*2048 + feat*2
//        (8 groups, 2 slots, 8 rows, 1024 bf16 features)
#define WS_FLAGS 512
#define WS_RING  4096

static __device__ __forceinline__ unsigned short f2bf(float f) {
    union { float f; unsigned int u; } v; v.f = f;
    return (unsigned short)((v.u + 0x7fffu + ((v.u >> 16) & 1u)) >> 16);
}

static __device__ __forceinline__ s16x8 pack8(float4 a, float4 b) {
    s16x8 v;
    v[0] = (short)f2bf(a.x); v[1] = (short)f2bf(a.y);
    v[2] = (short)f2bf(a.z); v[3] = (short)f2bf(a.w);
    v[4] = (short)f2bf(b.x); v[5] = (short)f2bf(b.y);
    v[6] = (short)f2bf(b.z); v[7] = (short)f2bf(b.w);
    return v;
}

static __device__ __forceinline__ f32x4 zero4() {
    f32x4 v = {0.f, 0.f, 0.f, 0.f};
    return v;
}

// Device-coherent-point access (r3/r5/r9/r10/r12-proven): sc0 sc1.
static __device__ __forceinline__ s16x8 ld16_sc01(const void* p) {
    s16x8 v;
    asm volatile("global_load_dwordx4 %0, %1, off sc0 sc1" : "=v"(v) : "v"(p));
    return v;
}
static __device__ __forceinline__ unsigned ld4_sc01_wait(const void* p) {
    unsigned v;
    asm volatile("global_load_dword %0, %1, off sc0 sc1\n\ts_waitcnt vmcnt(0)"
                 : "=v"(v) : "v"(p) : "memory");
    return v;
}
static __device__ __forceinline__ void st8_sc01(void* p, u32x2 v) {
    asm volatile("global_store_dwordx2 %0, %1, off sc0 sc1" :: "v"(p), "v"(v) : "memory");
}
#define WAITV(n) do { asm volatile("s_waitcnt vmcnt(" #n ")" ::: "memory"); \
                      __builtin_amdgcn_sched_barrier(0); } while (0)

// ---------------------------------------------------------------------------
// Kernel 0: zero the control region (flags) each launch.
// ---------------------------------------------------------------------------
__global__ void init_ws(unsigned int* w) {
    for (int i = threadIdx.x; i < 640; i += 256)
        __hip_atomic_store(&w[i], 0u, __ATOMIC_RELAXED, __HIP_MEMORY_SCOPE_AGENT);
}

// ---------------------------------------------------------------------------
// Kernel 1: xw = x @ W_ih^T + b_ih + b_hh -> d_out states area.
// XCD-chunked block remap: the 8 bn-blocks sharing an A-row-panel land on
// ONE XCD (launch id % 8 = XCD, round-robin) -> A re-reads become L2 hits.
// ---------------------------------------------------------------------------
__global__ __launch_bounds__(256, 3) void xw_gemm(
    const float* __restrict__ X,
    const float* __restrict__ Wih,
    const float* __restrict__ bih,
    const float* __restrict__ bhh,
    float* __restrict__ out)
{
    __shared__ unsigned short As[128 * 64];
    __shared__ unsigned short Bs[128 * 64];

    const int tid  = threadIdx.x;
    const int lane = tid & 63;
    const int wid  = tid >> 6;
    const int L  = blockIdx.x;
    const int bm = (L & 7) * 64 + (L >> 6);   // XCD (L%8) owns bm-panel chunk
    const int bn = (L >> 3) & 7;
    const size_t m0 = (size_t)bm * 128;
    const int n0 = bn * 128;
    const int wm = (wid >> 1) * 64;
    const int wn = (wid & 1) * 64;

    f32x4 acc[4][4];
#pragma unroll
    for (int i = 0; i < 4; ++i)
#pragma unroll
        for (int jj = 0; jj < 4; ++jj) acc[i][jj] = zero4();

    const int srow  = tid >> 1;
    const int shalf = tid & 1;
    const float* xp = X   + (m0 + srow) * (size_t)II + shalf * 32;
    const float* wp = Wih + (size_t)(n0 + srow) * II + shalf * 32;

    for (int kt = 0; kt < II / 64; ++kt) {
#pragma unroll
        for (int i = 0; i < 4; ++i) {
            float4 a0 = *(const float4*)(xp + i * 8);
            float4 a1 = *(const float4*)(xp + i * 8 + 4);
            float4 b0 = *(const float4*)(wp + i * 8);
            float4 b1 = *(const float4*)(wp + i * 8 + 4);
            const int c = shalf * 4 + i;
            const int cw = (c ^ (srow & 7)) << 3;
            *(s16x8*)&As[srow * 64 + cw] = pack8(a0, a1);
            *(s16x8*)&Bs[srow * 64 + cw] = pack8(b0, b1);
        }
        __syncthreads();

#pragma unroll
        for (int kk = 0; kk < 2; ++kk) {
            s16x8 af[4], bf[4];
            const int cs = kk * 4 + (lane >> 4);
#pragma unroll
            for (int mi = 0; mi < 4; ++mi) {
                const int r = wm + mi * 16 + (lane & 15);
                af[mi] = *(const s16x8*)&As[r * 64 + ((cs ^ (r & 7)) << 3)];
            }
#pragma unroll
            for (int ni = 0; ni < 4; ++ni) {
                const int r = wn + ni * 16 + (lane & 15);
                bf[ni] = *(const s16x8*)&Bs[r * 64 + ((cs ^ (r & 7)) << 3)];
            }
#pragma unroll
            for (int mi = 0; mi < 4; ++mi)
#pragma unroll
                for (int ni = 0; ni < 4; ++ni)
                    acc[mi][ni] = __builtin_amdgcn_mfma_f32_16x16x32_bf16(
                        af[mi], bf[ni], acc[mi][ni], 0, 0, 0);
        }
        __syncthreads();
        xp += 64; wp += 64;
    }

#pragma unroll
    for (int ni = 0; ni < 4; ++ni) {
        const int col = n0 + wn + ni * 16 + (lane & 15);
        const float bias = bih[col] + bhh[col];
#pragma unroll
        for (int mi = 0; mi < 4; ++mi) {
            const size_t row = m0 + wm + mi * 16 + ((lane >> 4) << 2);
#pragma unroll
            for (int r = 0; r < 4; ++r)
                out[(row + r) * (size_t)HH + col] = acc[mi][ni][r] + bias;
        }
    }
}

// ---------------------------------------------------------------------------
// Kernel 2: persistent scan (r12 MALL protocol, 8-block groups, per-wave
// poll+stage). 64 blocks x 512 thr (8 waves). 8 groups x 8 blocks; group
// owns batch rows [8g,8g+8); block = 128 feats (8 waves x 16, W in 128
// VGPR/wave as A-frags). Wave w polls ONLY producer-block w's flag
// (lane-uniform bypass dword) then stages its 2 KB slice -> barrier ->
// 32x(ds_read_b128+MFMA)/wave -> tanh -> ring store -> vmcnt(0) [MALL-only]
// -> barrier -> block flag (agent atomic) -> cached state stores (acks
// absorbed by next poll). No XCD/placement assumptions.
// ---------------------------------------------------------------------------
__global__ __launch_bounds__(512, 1) void rnn_scan(
    const float* __restrict__ Whh,
    float* __restrict__ out,
    void* __restrict__ ws)
{
    __shared__ unsigned short Hl[8 * 1024];   // 16 KiB staged hr tile

    const int tid  = threadIdx.x;
    const int lane = tid & 63;
    const int wid  = tid >> 6;
    const int g  = blockIdx.x >> 3;     // 0..7 batch group (8 rows)
    const int sl = blockIdx.x & 7;      // 0..7 feature slice (128 feats)

    const int jb = sl * 128 + wid * 16;           // wave's 16 output feats
    const int kg = lane >> 4;                     // k-subchunk / feat quarter

    // ---- one-time: wave's 16 W_hh rows -> 128 VGPRs of A-fragments ----
    s16x8 afr[32];
    {
        const float* wr = Whh + (size_t)(jb + (lane & 15)) * HH + kg * 8;
#pragma unroll
        for (int c = 0; c < 32; ++c) {
            float4 p0 = *(const float4*)(wr + c * 32);
            float4 p1 = *(const float4*)(wr + c * 32 + 4);
            afr[c] = pack8(p0, p1);
        }
    }

    unsigned* fl = (unsigned*)((char*)ws + WS_FLAGS) + g * 64;
    unsigned* myflag = fl + sl;
    char* rg = (char*)ws + WS_RING + (size_t)g * 32768;

    // per-wave staging: wave wid stages producer wid's slice (2 KB):
    // row = lane>>3 (0..7), 32 B at feat-offset wid*256 + (lane&7)*32
    const int strow = lane >> 3;
    const char* sbase0 = rg + strow * 2048 + wid * 256 + (lane & 7) * 32;
    const char* sbase1 = sbase0 + 16384;
    const int c0 = wid * 16 + (lane & 7) * 2;     // row-chunk index (16B units)

    // output mapping (D = W*hr): lane&15 = batch col; only bl<8 valid
    const int bl   = lane & 15;
    const int blv  = bl & 7;
    const int act  = bl < 8;
    const int b    = g * 8 + blv;
    const int f0   = jb + kg * 4;
    const int hrow = blv;

    float hprev[4];

    // ---- t = 0: h = tanh(xw); ring slot 1 -> drain -> flag -> states ----
    {
        const size_t idx = ((size_t)b * TT) * HH + f0;
        float4 xw4 = *(const float4*)(out + idx);
        float4 st;
        st.x = tanhf(xw4.x); st.y = tanhf(xw4.y);
        st.z = tanhf(xw4.z); st.w = tanhf(xw4.w);
        hprev[0] = st.x; hprev[1] = st.y; hprev[2] = st.z; hprev[3] = st.w;
        if (act) {
            u32x2 pk;
            pk[0] = (unsigned)f2bf(0.5f * st.x) | ((unsigned)f2bf(0.5f * st.y) << 16);
            pk[1] = (unsigned)f2bf(0.5f * st.z) | ((unsigned)f2bf(0.5f * st.w) << 16);
            st8_sc01(rg + 16384 + blv * 2048 + f0 * 2, pk);
        }
        asm volatile("s_waitcnt vmcnt(0)" ::: "memory");
        __syncthreads();
        if (tid == 0)
            __hip_atomic_store(myflag, 1u, __ATOMIC_RELAXED,
                               __HIP_MEMORY_SCOPE_AGENT);
        if (act) *(float4*)(out + idx) = st;
    }

#pragma unroll 1
    for (int t = 1; t < TT; ++t) {
        // ---- xw prefetch (cached; drained inside the poll) ----
        const size_t xidx = ((size_t)b * TT + t) * HH + f0;
        float4 xw4 = *(const float4*)(out + xidx);

        // ---- per-wave: poll own producer's flag (uniform), stage slice ----
        {
            for (;;) {
                unsigned v = ld4_sc01_wait(fl + wid);
                if (v >= (unsigned)t) break;     // lane-uniform exit
            }
            __builtin_amdgcn_sched_barrier(0);
            const char* sp = (t & 1) ? sbase1 : sbase0;
            s16x8 v0 = ld16_sc01(sp);
            s16x8 v1 = ld16_sc01(sp + 16);
            WAITV(1);
            *(s16x8*)&Hl[strow * 1024 + ((c0 ^ (strow & 7)) << 3)] = v0;
            WAITV(0);
            *(s16x8*)&Hl[strow * 1024 + (((c0 + 1) ^ (strow & 7)) << 3)] = v1;
        }
        __syncthreads();

        // ---- 32 x (ds_read_b128 B-frag + MFMA with VGPR A=W) ----
        f32x4 acc[4];
#pragma unroll
        for (int i = 0; i < 4; ++i) acc[i] = zero4();
#pragma unroll
        for (int kb = 0; kb < 4; ++kb) {
            s16x8 h8[8];
#pragma unroll
            for (int ki = 0; ki < 8; ++ki) {
                const int cs = (kb * 8 + ki) * 4 + kg;
                h8[ki] = *(const s16x8*)&Hl[hrow * 1024 + ((cs ^ (hrow & 7)) << 3)];
            }
#pragma unroll
            for (int ki = 0; ki < 8; ++ki)
                acc[ki & 3] = __builtin_amdgcn_mfma_f32_16x16x32_bf16(
                    afr[kb * 8 + ki], h8[ki], acc[ki & 3], 0, 0, 0);
        }
        f32x4 accT = acc[0] + acc[1] + acc[2] + acc[3];

        // ---- epilogue: tanh -> ring -> drain -> flag -> states ----
        {
            float hn[4];
#pragma unroll
            for (int r = 0; r < 4; ++r)
                hn[r] = tanhf(accT[r] + ((const float*)&xw4)[r]);
            float4 st; st.x = hn[0]; st.y = hn[1]; st.z = hn[2]; st.w = hn[3];
            if (t < TT - 1) {
                if (act) {
                    u32x2 pk;
                    pk[0] = (unsigned)f2bf(0.5f * (hn[0] + hprev[0])) |
                            ((unsigned)f2bf(0.5f * (hn[1] + hprev[1])) << 16);
                    pk[1] = (unsigned)f2bf(0.5f * (hn[2] + hprev[2])) |
                            ((unsigned)f2bf(0.5f * (hn[3] + hprev[3])) << 16);
                    char* rw = rg + (size_t)((t + 1) & 1) * 16384;
                    st8_sc01(rw + blv * 2048 + f0 * 2, pk);
                }
                asm volatile("s_waitcnt vmcnt(0)" ::: "memory");
                __syncthreads();   // ring drained by all waves; LDS reads done
                if (tid == 0)
                    __hip_atomic_store(myflag, (unsigned)(t + 1),
                                       __ATOMIC_RELAXED, __HIP_MEMORY_SCOPE_AGENT);
                if (act) *(float4*)(out + xidx) = st;   // acks absorb in poll
            } else {
                if (act) {
                    *(float4*)(out + xidx) = st;
                    *(float4*)(out + (size_t)BB * TT * HH + (size_t)b * HH + f0) = st;
                }
            }
#pragma unroll
            for (int r = 0; r < 4; ++r) hprev[r] = hn[r];
        }
    }
}

// ---------------------------------------------------------------------------
extern "C" void kernel_launch(void* const* d_in, const int* in_sizes, int n_in,
                              void* d_out, int out_size, void* d_ws, size_t ws_size,
                              hipStream_t stream)
{
    const float* X   = (const float*)d_in[0];
    const float* Wih = (const float*)d_in[1];
    const float* Whh = (const float*)d_in[2];
    const float* bih = (const float*)d_in[3];
    const float* bhh = (const float*)d_in[4];
    float* out = (float*)d_out;

    init_ws<<<dim3(1), dim3(256), 0, stream>>>((unsigned int*)d_ws);
    xw_gemm<<<dim3(4096), dim3(256), 0, stream>>>(X, Wih, bih, bhh, out);
    rnn_scan<<<dim3(64), dim3(512), 0, stream>>>(Whh, out, d_ws);
}

// Round 15
// 3563.919 us; speedup vs baseline: 1.1190x; 1.1190x over previous
//
#include <hip/hip_runtime.h>
#include <stdint.h>
#include <stddef.h>

#define TT 1024
#define BB 64
#define HH 1024
#define II 1024

typedef __attribute__((ext_vector_type(8))) short s16x8;
typedef __attribute__((ext_vector_type(4))) float f32x4;
typedef __attribute__((ext_vector_type(2))) unsigned u32x2;

// ---- workspace layout (bytes) ---- (proven footprint, <= 266240)
// 512  : flags[8][64] u32   (per group: words 0..15 used; 256 B stride)
// 4096 : ring: group*32768 + slot*16384 + row*2048 + feat*2
//        (8 groups, 2 slots, 8 rows, 1024 bf16 features)
#define WS_FLAGS 512
#define WS_RING  4096

static __device__ __forceinline__ unsigned short f2bf(float f) {
    union { float f; unsigned int u; } v; v.f = f;
    return (unsigned short)((v.u + 0x7fffu + ((v.u >> 16) & 1u)) >> 16);
}

static __device__ __forceinline__ s16x8 pack8(float4 a, float4 b) {
    s16x8 v;
    v[0] = (short)f2bf(a.x); v[1] = (short)f2bf(a.y);
    v[2] = (short)f2bf(a.z); v[3] = (short)f2bf(a.w);
    v[4] = (short)f2bf(b.x); v[5] = (short)f2bf(b.y);
    v[6] = (short)f2bf(b.z); v[7] = (short)f2bf(b.w);
    return v;
}

static __device__ __forceinline__ f32x4 zero4() {
    f32x4 v = {0.f, 0.f, 0.f, 0.f};
    return v;
}

// Device-coherent-point access (r3/r5/r9/r10/r12-proven): sc0 sc1.
static __device__ __forceinline__ s16x8 ld16_sc01(const void* p) {
    s16x8 v;
    asm volatile("global_load_dwordx4 %0, %1, off sc0 sc1" : "=v"(v) : "v"(p));
    return v;
}
static __device__ __forceinline__ unsigned ld4_sc01_wait(const void* p) {
    unsigned v;
    asm volatile("global_load_dword %0, %1, off sc0 sc1\n\ts_waitcnt vmcnt(0)"
                 : "=v"(v) : "v"(p) : "memory");
    return v;
}
static __device__ __forceinline__ void st8_sc01(void* p, u32x2 v) {
    asm volatile("global_store_dwordx2 %0, %1, off sc0 sc1" :: "v"(p), "v"(v) : "memory");
}
#define WAITV(n) do { asm volatile("s_waitcnt vmcnt(" #n ")" ::: "memory"); \
                      __builtin_amdgcn_sched_barrier(0); } while (0)

// ---------------------------------------------------------------------------
// Kernel 0: zero the control region (flags) each launch.
// ---------------------------------------------------------------------------
__global__ void init_ws(unsigned int* w) {
    for (int i = threadIdx.x; i < 640; i += 256)
        __hip_atomic_store(&w[i], 0u, __ATOMIC_RELAXED, __HIP_MEMORY_SCOPE_AGENT);
}

// ---------------------------------------------------------------------------
// Kernel 1: xw = x @ W_ih^T + b_ih + b_hh -> d_out states area.
// XCD-chunked remap (r14, bijective): 8 bn-blocks sharing an A-panel land
// on one XCD -> A re-reads become L2 hits.
// ---------------------------------------------------------------------------
__global__ __launch_bounds__(256, 3) void xw_gemm(
    const float* __restrict__ X,
    const float* __restrict__ Wih,
    const float* __restrict__ bih,
    const float* __restrict__ bhh,
    float* __restrict__ out)
{
    __shared__ unsigned short As[128 * 64];
    __shared__ unsigned short Bs[128 * 64];

    const int tid  = threadIdx.x;
    const int lane = tid & 63;
    const int wid  = tid >> 6;
    const int L  = blockIdx.x;
    const int bm = (L & 7) * 64 + (L >> 6);
    const int bn = (L >> 3) & 7;
    const size_t m0 = (size_t)bm * 128;
    const int n0 = bn * 128;
    const int wm = (wid >> 1) * 64;
    const int wn = (wid & 1) * 64;

    f32x4 acc[4][4];
#pragma unroll
    for (int i = 0; i < 4; ++i)
#pragma unroll
        for (int jj = 0; jj < 4; ++jj) acc[i][jj] = zero4();

    const int srow  = tid >> 1;
    const int shalf = tid & 1;
    const float* xp = X   + (m0 + srow) * (size_t)II + shalf * 32;
    const float* wp = Wih + (size_t)(n0 + srow) * II + shalf * 32;

    for (int kt = 0; kt < II / 64; ++kt) {
#pragma unroll
        for (int i = 0; i < 4; ++i) {
            float4 a0 = *(const float4*)(xp + i * 8);
            float4 a1 = *(const float4*)(xp + i * 8 + 4);
            float4 b0 = *(const float4*)(wp + i * 8);
            float4 b1 = *(const float4*)(wp + i * 8 + 4);
            const int c = shalf * 4 + i;
            const int cw = (c ^ (srow & 7)) << 3;
            *(s16x8*)&As[srow * 64 + cw] = pack8(a0, a1);
            *(s16x8*)&Bs[srow * 64 + cw] = pack8(b0, b1);
        }
        __syncthreads();

#pragma unroll
        for (int kk = 0; kk < 2; ++kk) {
            s16x8 af[4], bf[4];
            const int cs = kk * 4 + (lane >> 4);
#pragma unroll
            for (int mi = 0; mi < 4; ++mi) {
                const int r = wm + mi * 16 + (lane & 15);
                af[mi] = *(const s16x8*)&As[r * 64 + ((cs ^ (r & 7)) << 3)];
            }
#pragma unroll
            for (int ni = 0; ni < 4; ++ni) {
                const int r = wn + ni * 16 + (lane & 15);
                bf[ni] = *(const s16x8*)&Bs[r * 64 + ((cs ^ (r & 7)) << 3)];
            }
#pragma unroll
            for (int mi = 0; mi < 4; ++mi)
#pragma unroll
                for (int ni = 0; ni < 4; ++ni)
                    acc[mi][ni] = __builtin_amdgcn_mfma_f32_16x16x32_bf16(
                        af[mi], bf[ni], acc[mi][ni], 0, 0, 0);
        }
        __syncthreads();
        xp += 64; wp += 64;
    }

#pragma unroll
    for (int ni = 0; ni < 4; ++ni) {
        const int col = n0 + wn + ni * 16 + (lane & 15);
        const float bias = bih[col] + bhh[col];
#pragma unroll
        for (int mi = 0; mi < 4; ++mi) {
            const size_t row = m0 + wm + mi * 16 + ((lane >> 4) << 2);
#pragma unroll
            for (int r = 0; r < 4; ++r)
                out[(row + r) * (size_t)HH + col] = acc[mi][ni][r] + bias;
        }
    }
}

// ---------------------------------------------------------------------------
// Kernel 2: persistent scan (r12 structure; ONLY change: epilogue reorder —
// state stores AFTER flag publish, acks absorbed by next poll). 128 blocks
// x 256 thr (4 waves). 8 groups x 16 blocks; group owns batch rows
// [8g,8g+8); block = 64 feats (4 waves x 16, W in 128 VGPR/wave as A-frags).
// D = W*hr: lane owns 1 batch row (bl<8) x 4 consecutive features. Per
// step: all-lane poll of 16 per-block flags (coalesced bypass dword) ->
// cooperative 16 KB stage (sc0sc1, counted vmcnt) into XOR-swizzled LDS ->
// syncthreads -> 32x(ds_read_b128+MFMA)/wave -> tanh -> ring store ->
// vmcnt(0) [MALL acks only] -> syncthreads -> flag (agent atomic) ->
// cached state stores.
// ---------------------------------------------------------------------------
__global__ __launch_bounds__(256, 1) void rnn_scan(
    const float* __restrict__ Whh,
    float* __restrict__ out,
    void* __restrict__ ws)
{
    __shared__ unsigned short Hl[8 * 1024];   // 16 KiB staged hr tile

    const int tid  = threadIdx.x;
    const int lane = tid & 63;
    const int wid  = tid >> 6;
    const int g  = blockIdx.x >> 4;     // 0..7 batch group (8 rows)
    const int sl = blockIdx.x & 15;     // 0..15 feature slice (64 feats)

    const int jb = sl * 64 + wid * 16;            // wave's 16-feature block
    const int kg = lane >> 4;                     // k-subchunk / feat quarter

    // ---- one-time: wave's 16 W_hh rows -> 128 VGPRs of A-fragments ----
    s16x8 afr[32];
    {
        const float* wr = Whh + (size_t)(jb + (lane & 15)) * HH + kg * 8;
#pragma unroll
        for (int c = 0; c < 32; ++c) {
            float4 p0 = *(const float4*)(wr + c * 32);
            float4 p1 = *(const float4*)(wr + c * 32 + 4);
            afr[c] = pack8(p0, p1);
        }
    }

    unsigned* fl = (unsigned*)((char*)ws + WS_FLAGS) + g * 64;
    char* rg = (char*)ws + WS_RING + (size_t)g * 32768;

    // staging role: row tid>>5 (0..7), 16B seg tid&31; 4 chunks/thread
    const int srow = tid >> 5;
    const int sseg = tid & 31;
    const char* sbase0 = rg + srow * 2048 + sseg * 16;   // slot 0
    const char* sbase1 = sbase0 + 16384;                  // slot 1

    // output mapping (D = W*hr): lane&15 = batch col; only bl<8 valid
    const int bl   = lane & 15;
    const int blv  = bl & 7;
    const int act  = bl < 8;
    const int b    = g * 8 + blv;
    const int f0   = jb + kg * 4;
    const int hrow = blv;

    float hprev[4];

    // ---- t = 0: h = tanh(xw); ring slot 1 -> drain -> flag -> states ----
    {
        const size_t idx = ((size_t)b * TT) * HH + f0;
        float4 xw4 = *(const float4*)(out + idx);
        float4 st;
        st.x = tanhf(xw4.x); st.y = tanhf(xw4.y);
        st.z = tanhf(xw4.z); st.w = tanhf(xw4.w);
        hprev[0] = st.x; hprev[1] = st.y; hprev[2] = st.z; hprev[3] = st.w;
        if (act) {
            u32x2 pk;
            pk[0] = (unsigned)f2bf(0.5f * st.x) | ((unsigned)f2bf(0.5f * st.y) << 16);
            pk[1] = (unsigned)f2bf(0.5f * st.z) | ((unsigned)f2bf(0.5f * st.w) << 16);
            st8_sc01(rg + 16384 + blv * 2048 + f0 * 2, pk);
        }
        asm volatile("s_waitcnt vmcnt(0)" ::: "memory");
        __syncthreads();
        if (tid == 0)
            __hip_atomic_store(&fl[sl], 1u, __ATOMIC_RELAXED,
                               __HIP_MEMORY_SCOPE_AGENT);
        if (act) *(float4*)(out + idx) = st;
    }

#pragma unroll 1
    for (int t = 1; t < TT; ++t) {
        // ---- xw prefetch: issued now, drained inside the first poll iter ----
        const size_t xidx = ((size_t)b * TT + t) * HH + f0;
        float4 xw4 = *(const float4*)(out + xidx);

        // ---- poll 16 per-block flags (coalesced bypass, 1 line/wave) ----
        {
            const unsigned* myp = fl + (lane & 15);
            for (;;) {
                unsigned v = ld4_sc01_wait(myp);
                if (__all((int)(v >= (unsigned)t))) break;
                __builtin_amdgcn_s_sleep(1);
            }
            asm volatile("" ::: "memory");
            __builtin_amdgcn_sched_barrier(0);
        }

        // ---- cooperative stage: 16 KB tile, once per block, coalesced ----
        {
            const char* sp = (t & 1) ? sbase1 : sbase0;
            s16x8 v[4];
#pragma unroll
            for (int i = 0; i < 4; ++i) v[i] = ld16_sc01(sp + i * 512);
#pragma unroll
            for (int i = 0; i < 4; ++i) {
                if (i == 0)      { WAITV(3); }
                else if (i == 1) { WAITV(2); }
                else if (i == 2) { WAITV(1); }
                else             { WAITV(0); }
                const int c = sseg + i * 32;                  // chunk 0..127
                *(s16x8*)&Hl[srow * 1024 + ((c ^ (srow & 7)) << 3)] = v[i];
            }
        }
        __syncthreads();

        // ---- 32 x (ds_read_b128 B-frag + MFMA with VGPR A=W) ----
        f32x4 acc[4];
#pragma unroll
        for (int i = 0; i < 4; ++i) acc[i] = zero4();
#pragma unroll
        for (int kb = 0; kb < 4; ++kb) {
            s16x8 h8[8];
#pragma unroll
            for (int ki = 0; ki < 8; ++ki) {
                const int cs = (kb * 8 + ki) * 4 + kg;
                h8[ki] = *(const s16x8*)&Hl[hrow * 1024 + ((cs ^ (hrow & 7)) << 3)];
            }
#pragma unroll
            for (int ki = 0; ki < 8; ++ki)
                acc[ki & 3] = __builtin_amdgcn_mfma_f32_16x16x32_bf16(
                    afr[kb * 8 + ki], h8[ki], acc[ki & 3], 0, 0, 0);
        }
        f32x4 accT = acc[0] + acc[1] + acc[2] + acc[3];

        // ---- epilogue: tanh -> ring -> drain -> barrier -> flag -> states ----
        {
            float hn[4];
#pragma unroll
            for (int r = 0; r < 4; ++r)
                hn[r] = tanhf(accT[r] + ((const float*)&xw4)[r]);
            float4 st; st.x = hn[0]; st.y = hn[1]; st.z = hn[2]; st.w = hn[3];
            if (t < TT - 1) {
                if (act) {
                    u32x2 pk;
                    pk[0] = (unsigned)f2bf(0.5f * (hn[0] + hprev[0])) |
                            ((unsigned)f2bf(0.5f * (hn[1] + hprev[1])) << 16);
                    pk[1] = (unsigned)f2bf(0.5f * (hn[2] + hprev[2])) |
                            ((unsigned)f2bf(0.5f * (hn[3] + hprev[3])) << 16);
                    char* rw = rg + (size_t)((t + 1) & 1) * 16384;
                    st8_sc01(rw + blv * 2048 + f0 * 2, pk);
                }
                asm volatile("s_waitcnt vmcnt(0)" ::: "memory");
                __syncthreads();   // ring drained; LDS reads done
                if (tid == 0)
                    __hip_atomic_store(&fl[sl], (unsigned)(t + 1),
                                       __ATOMIC_RELAXED, __HIP_MEMORY_SCOPE_AGENT);
                if (act) *(float4*)(out + xidx) = st;  // acks absorb in next poll
            } else {
                if (act) {
                    *(float4*)(out + xidx) = st;
                    *(float4*)(out + (size_t)BB * TT * HH + (size_t)b * HH + f0) = st;
                }
            }
#pragma unroll
            for (int r = 0; r < 4; ++r) hprev[r] = hn[r];
        }
    }
}

// ---------------------------------------------------------------------------
extern "C" void kernel_launch(void* const* d_in, const int* in_sizes, int n_in,
                              void* d_out, int out_size, void* d_ws, size_t ws_size,
                              hipStream_t stream)
{
    const float* X   = (const float*)d_in[0];
    const float* Wih = (const float*)d_in[1];
    const float* Whh = (const float*)d_in[2];
    const float* bih = (const float*)d_in[3];
    const float* bhh = (const float*)d_in[4];
    float* out = (float*)d_out;

    init_ws<<<dim3(1), dim3(256), 0, stream>>>((unsigned int*)d_ws);
    xw_gemm<<<dim3(4096), dim3(256), 0, stream>>>(X, Wih, bih, bhh, out);
    rnn_scan<<<dim3(128), dim3(256), 0, stream>>>(Whh, out, d_ws);
}

// Round 16
// 3460.378 us; speedup vs baseline: 1.1525x; 1.0299x over previous
//
#include <hip/hip_runtime.h>
#include <stdint.h>
#include <stddef.h>

#define TT 1024
#define BB 64
#define HH 1024
#define II 1024

typedef __attribute__((ext_vector_type(8))) short s16x8;
typedef __attribute__((ext_vector_type(4))) float f32x4;
typedef __attribute__((ext_vector_type(2))) unsigned u32x2;

// ---- workspace layout (bytes) ---- (proven footprint, <= 266240)
// 0    : flags: flag(g,sl) at byte g*512 + sl*32  (32B stride: 2 producers
//        per 64B line instead of 16 -> avoids MALL line-write serialization)
// 4096 : ring: group*32768 + slot*16384 + row*2048 + feat*2
//        (8 groups, 2 slots, 8 rows, 1024 bf16 features)
#define WS_RING  4096

// packed RNE f32->bf16 via HW v_cvt_pk_bf16_f32 (T12; non-volatile so the
// scheduler can interleave). Replaces ~4-5 integer VALU ops per element.
static __device__ __forceinline__ unsigned cvtpk(float lo, float hi) {
    unsigned r;
    asm("v_cvt_pk_bf16_f32 %0, %1, %2" : "=v"(r) : "v"(lo), "v"(hi));
    return r;
}

static __device__ __forceinline__ s16x8 pack8(float4 a, float4 b) {
    union { unsigned u[4]; s16x8 v; } r;
    r.u[0] = cvtpk(a.x, a.y);
    r.u[1] = cvtpk(a.z, a.w);
    r.u[2] = cvtpk(b.x, b.y);
    r.u[3] = cvtpk(b.z, b.w);
    return r.v;
}

static __device__ __forceinline__ f32x4 zero4() {
    f32x4 v = {0.f, 0.f, 0.f, 0.f};
    return v;
}

// Device-coherent-point access (r3/r5/r9/r10/r12-proven): sc0 sc1.
static __device__ __forceinline__ s16x8 ld16_sc01(const void* p) {
    s16x8 v;
    asm volatile("global_load_dwordx4 %0, %1, off sc0 sc1" : "=v"(v) : "v"(p));
    return v;
}
static __device__ __forceinline__ unsigned ld4_sc01_wait(const void* p) {
    unsigned v;
    asm volatile("global_load_dword %0, %1, off sc0 sc1\n\ts_waitcnt vmcnt(0)"
                 : "=v"(v) : "v"(p) : "memory");
    return v;
}
static __device__ __forceinline__ void st8_sc01(void* p, u32x2 v) {
    asm volatile("global_store_dwordx2 %0, %1, off sc0 sc1" :: "v"(p), "v"(v) : "memory");
}
#define WAITV(n) do { asm volatile("s_waitcnt vmcnt(" #n ")" ::: "memory"); \
                      __builtin_amdgcn_sched_barrier(0); } while (0)

// ---------------------------------------------------------------------------
// Kernel 0: zero the control region (full 4 KB flag area) each launch.
// ---------------------------------------------------------------------------
__global__ void init_ws(unsigned int* w) {
    for (int i = threadIdx.x; i < 1024; i += 256)
        __hip_atomic_store(&w[i], 0u, __ATOMIC_RELAXED, __HIP_MEMORY_SCOPE_AGENT);
}

// ---------------------------------------------------------------------------
// Kernel 1: xw = x @ W_ih^T + b_ih + b_hh -> d_out states area.
// Only change vs r15: pack8 now uses v_cvt_pk_bf16_f32 (staging was
// conversion-VALU-bound: ~400 integer ops/iter -> ~40 cvt ops).
// ---------------------------------------------------------------------------
__global__ __launch_bounds__(256, 3) void xw_gemm(
    const float* __restrict__ X,
    const float* __restrict__ Wih,
    const float* __restrict__ bih,
    const float* __restrict__ bhh,
    float* __restrict__ out)
{
    __shared__ unsigned short As[128 * 64];
    __shared__ unsigned short Bs[128 * 64];

    const int tid  = threadIdx.x;
    const int lane = tid & 63;
    const int wid  = tid >> 6;
    const int L  = blockIdx.x;
    const int bm = (L & 7) * 64 + (L >> 6);
    const int bn = (L >> 3) & 7;
    const size_t m0 = (size_t)bm * 128;
    const int n0 = bn * 128;
    const int wm = (wid >> 1) * 64;
    const int wn = (wid & 1) * 64;

    f32x4 acc[4][4];
#pragma unroll
    for (int i = 0; i < 4; ++i)
#pragma unroll
        for (int jj = 0; jj < 4; ++jj) acc[i][jj] = zero4();

    const int srow  = tid >> 1;
    const int shalf = tid & 1;
    const float* xp = X   + (m0 + srow) * (size_t)II + shalf * 32;
    const float* wp = Wih + (size_t)(n0 + srow) * II + shalf * 32;

    for (int kt = 0; kt < II / 64; ++kt) {
#pragma unroll
        for (int i = 0; i < 4; ++i) {
            float4 a0 = *(const float4*)(xp + i * 8);
            float4 a1 = *(const float4*)(xp + i * 8 + 4);
            float4 b0 = *(const float4*)(wp + i * 8);
            float4 b1 = *(const float4*)(wp + i * 8 + 4);
            const int c = shalf * 4 + i;
            const int cw = (c ^ (srow & 7)) << 3;
            *(s16x8*)&As[srow * 64 + cw] = pack8(a0, a1);
            *(s16x8*)&Bs[srow * 64 + cw] = pack8(b0, b1);
        }
        __syncthreads();

#pragma unroll
        for (int kk = 0; kk < 2; ++kk) {
            s16x8 af[4], bf[4];
            const int cs = kk * 4 + (lane >> 4);
#pragma unroll
            for (int mi = 0; mi < 4; ++mi) {
                const int r = wm + mi * 16 + (lane & 15);
                af[mi] = *(const s16x8*)&As[r * 64 + ((cs ^ (r & 7)) << 3)];
            }
#pragma unroll
            for (int ni = 0; ni < 4; ++ni) {
                const int r = wn + ni * 16 + (lane & 15);
                bf[ni] = *(const s16x8*)&Bs[r * 64 + ((cs ^ (r & 7)) << 3)];
            }
#pragma unroll
            for (int mi = 0; mi < 4; ++mi)
#pragma unroll
                for (int ni = 0; ni < 4; ++ni)
                    acc[mi][ni] = __builtin_amdgcn_mfma_f32_16x16x32_bf16(
                        af[mi], bf[ni], acc[mi][ni], 0, 0, 0);
        }
        __syncthreads();
        xp += 64; wp += 64;
    }

#pragma unroll
    for (int ni = 0; ni < 4; ++ni) {
        const int col = n0 + wn + ni * 16 + (lane & 15);
        const float bias = bih[col] + bhh[col];
#pragma unroll
        for (int mi = 0; mi < 4; ++mi) {
            const size_t row = m0 + wm + mi * 16 + ((lane >> 4) << 2);
#pragma unroll
            for (int r = 0; r < 4; ++r)
                out[(row + r) * (size_t)HH + col] = acc[mi][ni][r] + bias;
        }
    }
}

// ---------------------------------------------------------------------------
// Kernel 2: persistent scan (r15 structure). Changes: (a) flags spread to
// 32B stride (2 producer stores per 64B line, not 16 -> kills potential
// MALL line-write serialization on the flag line); (b) epilogue bf16 packs
// via v_cvt_pk_bf16_f32 (~100cy off the critical chain). Everything else
// r15-verbatim: 128 blocks x 256 thr; 8 groups x 16 blocks; group owns
// batch rows [8g,8g+8); block = 64 feats; W in 128 VGPR/wave; D = W*hr.
// ---------------------------------------------------------------------------
__global__ __launch_bounds__(256, 1) void rnn_scan(
    const float* __restrict__ Whh,
    float* __restrict__ out,
    void* __restrict__ ws)
{
    __shared__ unsigned short Hl[8 * 1024];   // 16 KiB staged hr tile

    const int tid  = threadIdx.x;
    const int lane = tid & 63;
    const int wid  = tid >> 6;
    const int g  = blockIdx.x >> 4;     // 0..7 batch group (8 rows)
    const int sl = blockIdx.x & 15;     // 0..15 feature slice (64 feats)

    const int jb = sl * 64 + wid * 16;            // wave's 16-feature block
    const int kg = lane >> 4;                     // k-subchunk / feat quarter

    // ---- one-time: wave's 16 W_hh rows -> 128 VGPRs of A-fragments ----
    s16x8 afr[32];
    {
        const float* wr = Whh + (size_t)(jb + (lane & 15)) * HH + kg * 8;
#pragma unroll
        for (int c = 0; c < 32; ++c) {
            float4 p0 = *(const float4*)(wr + c * 32);
            float4 p1 = *(const float4*)(wr + c * 32 + 4);
            afr[c] = pack8(p0, p1);
        }
    }

    // flags: flag(g,sl) at dword offset g*128 + sl*8 (32B stride)
    unsigned* fl = (unsigned*)ws + g * 128;
    unsigned* myflag = fl + sl * 8;
    char* rg = (char*)ws + WS_RING + (size_t)g * 32768;

    // staging role: row tid>>5 (0..7), 16B seg tid&31; 4 chunks/thread
    const int srow = tid >> 5;
    const int sseg = tid & 31;
    const char* sbase0 = rg + srow * 2048 + sseg * 16;   // slot 0
    const char* sbase1 = sbase0 + 16384;                  // slot 1

    // output mapping (D = W*hr): lane&15 = batch col; only bl<8 valid
    const int bl   = lane & 15;
    const int blv  = bl & 7;
    const int act  = bl < 8;
    const int b    = g * 8 + blv;
    const int f0   = jb + kg * 4;
    const int hrow = blv;

    float hprev[4];

    // ---- t = 0: h = tanh(xw); ring slot 1 -> drain -> flag -> states ----
    {
        const size_t idx = ((size_t)b * TT) * HH + f0;
        float4 xw4 = *(const float4*)(out + idx);
        float4 st;
        st.x = tanhf(xw4.x); st.y = tanhf(xw4.y);
        st.z = tanhf(xw4.z); st.w = tanhf(xw4.w);
        hprev[0] = st.x; hprev[1] = st.y; hprev[2] = st.z; hprev[3] = st.w;
        if (act) {
            u32x2 pk;
            pk[0] = cvtpk(0.5f * st.x, 0.5f * st.y);
            pk[1] = cvtpk(0.5f * st.z, 0.5f * st.w);
            st8_sc01(rg + 16384 + blv * 2048 + f0 * 2, pk);
        }
        asm volatile("s_waitcnt vmcnt(0)" ::: "memory");
        __syncthreads();
        if (tid == 0)
            __hip_atomic_store(myflag, 1u, __ATOMIC_RELAXED,
                               __HIP_MEMORY_SCOPE_AGENT);
        if (act) *(float4*)(out + idx) = st;
    }

#pragma unroll 1
    for (int t = 1; t < TT; ++t) {
        // ---- xw prefetch: issued now, drained inside the first poll iter ----
        const size_t xidx = ((size_t)b * TT + t) * HH + f0;
        float4 xw4 = *(const float4*)(out + xidx);

        // ---- poll 16 per-block flags (bypass dword, 32B-strided words) ----
        {
            const unsigned* myp = fl + (lane & 15) * 8;
            for (;;) {
                unsigned v = ld4_sc01_wait(myp);
                if (__all((int)(v >= (unsigned)t))) break;
                __builtin_amdgcn_s_sleep(1);
            }
            asm volatile("" ::: "memory");
            __builtin_amdgcn_sched_barrier(0);
        }

        // ---- cooperative stage: 16 KB tile, once per block, coalesced ----
        {
            const char* sp = (t & 1) ? sbase1 : sbase0;
            s16x8 v[4];
#pragma unroll
            for (int i = 0; i < 4; ++i) v[i] = ld16_sc01(sp + i * 512);
#pragma unroll
            for (int i = 0; i < 4; ++i) {
                if (i == 0)      { WAITV(3); }
                else if (i == 1) { WAITV(2); }
                else if (i == 2) { WAITV(1); }
                else             { WAITV(0); }
                const int c = sseg + i * 32;                  // chunk 0..127
                *(s16x8*)&Hl[srow * 1024 + ((c ^ (srow & 7)) << 3)] = v[i];
            }
        }
        __syncthreads();

        // ---- 32 x (ds_read_b128 B-frag + MFMA with VGPR A=W) ----
        f32x4 acc[4];
#pragma unroll
        for (int i = 0; i < 4; ++i) acc[i] = zero4();
#pragma unroll
        for (int kb = 0; kb < 4; ++kb) {
            s16x8 h8[8];
#pragma unroll
            for (int ki = 0; ki < 8; ++ki) {
                const int cs = (kb * 8 + ki) * 4 + kg;
                h8[ki] = *(const s16x8*)&Hl[hrow * 1024 + ((cs ^ (hrow & 7)) << 3)];
            }
#pragma unroll
            for (int ki = 0; ki < 8; ++ki)
                acc[ki & 3] = __builtin_amdgcn_mfma_f32_16x16x32_bf16(
                    afr[kb * 8 + ki], h8[ki], acc[ki & 3], 0, 0, 0);
        }
        f32x4 accT = acc[0] + acc[1] + acc[2] + acc[3];

        // ---- epilogue: tanh -> ring (cvt_pk) -> drain -> flag -> states ----
        {
            float hn[4];
#pragma unroll
            for (int r = 0; r < 4; ++r)
                hn[r] = tanhf(accT[r] + ((const float*)&xw4)[r]);
            float4 st; st.x = hn[0]; st.y = hn[1]; st.z = hn[2]; st.w = hn[3];
            if (t < TT - 1) {
                if (act) {
                    u32x2 pk;
                    pk[0] = cvtpk(0.5f * (hn[0] + hprev[0]),
                                  0.5f * (hn[1] + hprev[1]));
                    pk[1] = cvtpk(0.5f * (hn[2] + hprev[2]),
                                  0.5f * (hn[3] + hprev[3]));
                    char* rw = rg + (size_t)((t + 1) & 1) * 16384;
                    st8_sc01(rw + blv * 2048 + f0 * 2, pk);
                }
                asm volatile("s_waitcnt vmcnt(0)" ::: "memory");
                __syncthreads();   // ring drained; LDS reads done
                if (tid == 0)
                    __hip_atomic_store(myflag, (unsigned)(t + 1),
                                       __ATOMIC_RELAXED, __HIP_MEMORY_SCOPE_AGENT);
                if (act) *(float4*)(out + xidx) = st;  // acks absorb in next poll
            } else {
                if (act) {
                    *(float4*)(out + xidx) = st;
                    *(float4*)(out + (size_t)BB * TT * HH + (size_t)b * HH + f0) = st;
                }
            }
#pragma unroll
            for (int r = 0; r < 4; ++r) hprev[r] = hn[r];
        }
    }
}

// ---------------------------------------------------------------------------
extern "C" void kernel_launch(void* const* d_in, const int* in_sizes, int n_in,
                              void* d_out, int out_size, void* d_ws, size_t ws_size,
                              hipStream_t stream)
{
    const float* X   = (const float*)d_in[0];
    const float* Wih = (const float*)d_in[1];
    const float* Whh = (const float*)d_in[2];
    const float* bih = (const float*)d_in[3];
    const float* bhh = (const float*)d_in[4];
    float* out = (float*)d_out;

    init_ws<<<dim3(1), dim3(256), 0, stream>>>((unsigned int*)d_ws);
    xw_gemm<<<dim3(4096), dim3(256), 0, stream>>>(X, Wih, bih, bhh, out);
    rnn_scan<<<dim3(128), dim3(256), 0, stream>>>(Whh, out, d_ws);
}

// Round 17
// 3366.373 us; speedup vs baseline: 1.1847x; 1.0279x over previous
//
#include <hip/hip_runtime.h>
#include <stdint.h>
#include <stddef.h>

#define TT 1024
#define BB 64
#define HH 1024
#define II 1024

typedef __attribute__((ext_vector_type(8))) short s16x8;
typedef __attribute__((ext_vector_type(4))) float f32x4;
typedef __attribute__((ext_vector_type(4))) unsigned u32x4;
typedef __attribute__((ext_vector_type(2))) unsigned u32x2;

// ---- workspace layout (bytes) ---- (proven footprint, <= 266240)
// 0    : flags: flag(g,sl) at byte g*512 + sl*32  (32B stride, r16-proven)
// 4096 : ring: group*32768 + slot*16384 + row*2048 + feat*2
//        (8 groups, 2 slots, 8 rows, 1024 bf16 features)
#define WS_RING  4096

// packed RNE f32->bf16 via HW v_cvt_pk_bf16_f32 (T12).
static __device__ __forceinline__ unsigned cvtpk(float lo, float hi) {
    unsigned r;
    asm("v_cvt_pk_bf16_f32 %0, %1, %2" : "=v"(r) : "v"(lo), "v"(hi));
    return r;
}
static __device__ __forceinline__ u32x4 pk4(float4 a, float4 b) {
    u32x4 r;
    r[0] = cvtpk(a.x, a.y); r[1] = cvtpk(a.z, a.w);
    r[2] = cvtpk(b.x, b.y); r[3] = cvtpk(b.z, b.w);
    return r;
}

static __device__ __forceinline__ f32x4 zero4() {
    f32x4 v = {0.f, 0.f, 0.f, 0.f};
    return v;
}

// Device-coherent-point access (r3/r5/r9/r10/r12-proven): sc0 sc1.
static __device__ __forceinline__ s16x8 ld16_sc01(const void* p) {
    s16x8 v;
    asm volatile("global_load_dwordx4 %0, %1, off sc0 sc1" : "=v"(v) : "v"(p));
    return v;
}
static __device__ __forceinline__ unsigned ld4_sc01_wait(const void* p) {
    unsigned v;
    asm volatile("global_load_dword %0, %1, off sc0 sc1\n\ts_waitcnt vmcnt(0)"
                 : "=v"(v) : "v"(p) : "memory");
    return v;
}
static __device__ __forceinline__ void st8_sc01(void* p, u32x2 v) {
    asm volatile("global_store_dwordx2 %0, %1, off sc0 sc1" :: "v"(p), "v"(v) : "memory");
}
#define WAITV(n) do { asm volatile("s_waitcnt vmcnt(" #n ")" ::: "memory"); \
                      __builtin_amdgcn_sched_barrier(0); } while (0)

// ---------------------------------------------------------------------------
// Kernel 0: zero the control region (flags) each launch.
// ---------------------------------------------------------------------------
__global__ void init_ws(unsigned int* w) {
    for (int i = threadIdx.x; i < 1024; i += 256)
        __hip_atomic_store(&w[i], 0u, __ATOMIC_RELAXED, __HIP_MEMORY_SCOPE_AGENT);
}

// ---------------------------------------------------------------------------
// Kernel 1: xw = x @ W_ih^T + b_ih + b_hh -> d_out states area.
// Software-pipelined: LDS double-buffer (64 KiB), issue next K-tile's global
// loads BEFORE the MFMA phase (latency hides under MFMA+ds_read), convert+
// write the other buffer after, ONE barrier per iter. launch_bounds(256,2)
// (prefetch regs need the 256-VGPR budget; 2 blocks/CU at 64 KiB LDS).
// ---------------------------------------------------------------------------
__global__ __launch_bounds__(256, 2) void xw_gemm(
    const float* __restrict__ X,
    const float* __restrict__ Wih,
    const float* __restrict__ bih,
    const float* __restrict__ bhh,
    float* __restrict__ out)
{
    __shared__ unsigned short As[2][128 * 64];   // 32 KiB
    __shared__ unsigned short Bs[2][128 * 64];   // 32 KiB

    const int tid  = threadIdx.x;
    const int lane = tid & 63;
    const int wid  = tid >> 6;
    const int L  = blockIdx.x;
    const int bm = (L & 7) * 64 + (L >> 6);   // XCD-chunked remap (r14)
    const int bn = (L >> 3) & 7;
    const size_t m0 = (size_t)bm * 128;
    const int n0 = bn * 128;
    const int wm = (wid >> 1) * 64;
    const int wn = (wid & 1) * 64;

    f32x4 acc[4][4];
#pragma unroll
    for (int i = 0; i < 4; ++i)
#pragma unroll
        for (int jj = 0; jj < 4; ++jj) acc[i][jj] = zero4();

    const int srow  = tid >> 1;
    const int shalf = tid & 1;
    const float* xp = X   + (m0 + srow) * (size_t)II + shalf * 32;
    const float* wp = Wih + (size_t)(n0 + srow) * II + shalf * 32;

    float4 a4[8], b4[8];

    // ---- prologue: load + convert + write buffer 0 ----
#pragma unroll
    for (int i = 0; i < 4; ++i) {
        a4[2 * i]     = *(const float4*)(xp + i * 8);
        a4[2 * i + 1] = *(const float4*)(xp + i * 8 + 4);
        b4[2 * i]     = *(const float4*)(wp + i * 8);
        b4[2 * i + 1] = *(const float4*)(wp + i * 8 + 4);
    }
#pragma unroll
    for (int i = 0; i < 4; ++i) {
        const int c = shalf * 4 + i;
        const int cw = (c ^ (srow & 7)) << 3;
        *(u32x4*)&As[0][srow * 64 + cw] = pk4(a4[2 * i], a4[2 * i + 1]);
        *(u32x4*)&Bs[0][srow * 64 + cw] = pk4(b4[2 * i], b4[2 * i + 1]);
    }
    __syncthreads();

#pragma unroll 1
    for (int kt = 0; kt < 16; ++kt) {
        const int cur = kt & 1, nxt = cur ^ 1;

        // ---- issue next K-tile's loads (in flight under the MFMA phase) ----
        if (kt < 15) {
            xp += 64; wp += 64;
#pragma unroll
            for (int i = 0; i < 4; ++i) {
                a4[2 * i]     = *(const float4*)(xp + i * 8);
                a4[2 * i + 1] = *(const float4*)(xp + i * 8 + 4);
                b4[2 * i]     = *(const float4*)(wp + i * 8);
                b4[2 * i + 1] = *(const float4*)(wp + i * 8 + 4);
            }
            __builtin_amdgcn_sched_barrier(0);   // keep load issue above MFMA
        }

        // ---- MFMA on buffer cur ----
#pragma unroll
        for (int kk = 0; kk < 2; ++kk) {
            s16x8 af[4], bf[4];
            const int cs = kk * 4 + (lane >> 4);
#pragma unroll
            for (int mi = 0; mi < 4; ++mi) {
                const int r = wm + mi * 16 + (lane & 15);
                af[mi] = *(const s16x8*)&As[cur][r * 64 + ((cs ^ (r & 7)) << 3)];
            }
#pragma unroll
            for (int ni = 0; ni < 4; ++ni) {
                const int r = wn + ni * 16 + (lane & 15);
                bf[ni] = *(const s16x8*)&Bs[cur][r * 64 + ((cs ^ (r & 7)) << 3)];
            }
#pragma unroll
            for (int mi = 0; mi < 4; ++mi)
#pragma unroll
                for (int ni = 0; ni < 4; ++ni)
                    acc[mi][ni] = __builtin_amdgcn_mfma_f32_16x16x32_bf16(
                        af[mi], bf[ni], acc[mi][ni], 0, 0, 0);
        }

        // ---- convert + write buffer nxt (waits the loads here) ----
        if (kt < 15) {
#pragma unroll
            for (int i = 0; i < 4; ++i) {
                const int c = shalf * 4 + i;
                const int cw = (c ^ (srow & 7)) << 3;
                *(u32x4*)&As[nxt][srow * 64 + cw] = pk4(a4[2 * i], a4[2 * i + 1]);
                *(u32x4*)&Bs[nxt][srow * 64 + cw] = pk4(b4[2 * i], b4[2 * i + 1]);
            }
        }
        __syncthreads();   // single barrier: cur reads done, nxt writes visible
    }

#pragma unroll
    for (int ni = 0; ni < 4; ++ni) {
        const int col = n0 + wn + ni * 16 + (lane & 15);
        const float bias = bih[col] + bhh[col];
#pragma unroll
        for (int mi = 0; mi < 4; ++mi) {
            const size_t row = m0 + wm + mi * 16 + ((lane >> 4) << 2);
#pragma unroll
            for (int r = 0; r < 4; ++r)
                out[(row + r) * (size_t)HH + col] = acc[mi][ni][r] + bias;
        }
    }
}

// ---------------------------------------------------------------------------
// Kernel 2: persistent scan — r16 VERBATIM (best: 2810 µs). 128 blocks x
// 256 thr; 8 groups x 16 blocks; group owns batch rows [8g,8g+8); block =
// 64 feats (4 waves x 16, W in 128 VGPR/wave as A-frags). D = W*hr. Flags
// 32B-strided. Poll (coalesced bypass) -> coop 16 KB stage -> XOR-swizzled
// LDS -> 32x(ds_read_b128+MFMA) -> tanh -> ring (cvt_pk) -> drain -> flag
// -> cached state stores.
// ---------------------------------------------------------------------------
__global__ __launch_bounds__(256, 1) void rnn_scan(
    const float* __restrict__ Whh,
    float* __restrict__ out,
    void* __restrict__ ws)
{
    __shared__ unsigned short Hl[8 * 1024];   // 16 KiB staged hr tile

    const int tid  = threadIdx.x;
    const int lane = tid & 63;
    const int wid  = tid >> 6;
    const int g  = blockIdx.x >> 4;     // 0..7 batch group (8 rows)
    const int sl = blockIdx.x & 15;     // 0..15 feature slice (64 feats)

    const int jb = sl * 64 + wid * 16;            // wave's 16-feature block
    const int kg = lane >> 4;                     // k-subchunk / feat quarter

    // ---- one-time: wave's 16 W_hh rows -> 128 VGPRs of A-fragments ----
    s16x8 afr[32];
    {
        const float* wr = Whh + (size_t)(jb + (lane & 15)) * HH + kg * 8;
#pragma unroll
        for (int c = 0; c < 32; ++c) {
            float4 p0 = *(const float4*)(wr + c * 32);
            float4 p1 = *(const float4*)(wr + c * 32 + 4);
            union { u32x4 u; s16x8 v; } cv;
            cv.u = pk4(p0, p1);
            afr[c] = cv.v;
        }
    }

    // flags: flag(g,sl) at dword offset g*128 + sl*8 (32B stride)
    unsigned* fl = (unsigned*)ws + g * 128;
    unsigned* myflag = fl + sl * 8;
    char* rg = (char*)ws + WS_RING + (size_t)g * 32768;

    // staging role: row tid>>5 (0..7), 16B seg tid&31; 4 chunks/thread
    const int srow = tid >> 5;
    const int sseg = tid & 31;
    const char* sbase0 = rg + srow * 2048 + sseg * 16;   // slot 0
    const char* sbase1 = sbase0 + 16384;                  // slot 1

    // output mapping (D = W*hr): lane&15 = batch col; only bl<8 valid
    const int bl   = lane & 15;
    const int blv  = bl & 7;
    const int act  = bl < 8;
    const int b    = g * 8 + blv;
    const int f0   = jb + kg * 4;
    const int hrow = blv;

    float hprev[4];

    // ---- t = 0: h = tanh(xw); ring slot 1 -> drain -> flag -> states ----
    {
        const size_t idx = ((size_t)b * TT) * HH + f0;
        float4 xw4 = *(const float4*)(out + idx);
        float4 st;
        st.x = tanhf(xw4.x); st.y = tanhf(xw4.y);
        st.z = tanhf(xw4.z); st.w = tanhf(xw4.w);
        hprev[0] = st.x; hprev[1] = st.y; hprev[2] = st.z; hprev[3] = st.w;
        if (act) {
            u32x2 pk;
            pk[0] = cvtpk(0.5f * st.x, 0.5f * st.y);
            pk[1] = cvtpk(0.5f * st.z, 0.5f * st.w);
            st8_sc01(rg + 16384 + blv * 2048 + f0 * 2, pk);
        }
        asm volatile("s_waitcnt vmcnt(0)" ::: "memory");
        __syncthreads();
        if (tid == 0)
            __hip_atomic_store(myflag, 1u, __ATOMIC_RELAXED,
                               __HIP_MEMORY_SCOPE_AGENT);
        if (act) *(float4*)(out + idx) = st;
    }

#pragma unroll 1
    for (int t = 1; t < TT; ++t) {
        // ---- xw prefetch: issued now, drained inside the first poll iter ----
        const size_t xidx = ((size_t)b * TT + t) * HH + f0;
        float4 xw4 = *(const float4*)(out + xidx);

        // ---- poll 16 per-block flags (bypass dword, 32B-strided words) ----
        {
            const unsigned* myp = fl + (lane & 15) * 8;
            for (;;) {
                unsigned v = ld4_sc01_wait(myp);
                if (__all((int)(v >= (unsigned)t))) break;
                __builtin_amdgcn_s_sleep(1);
            }
            asm volatile("" ::: "memory");
            __builtin_amdgcn_sched_barrier(0);
        }

        // ---- cooperative stage: 16 KB tile, once per block, coalesced ----
        {
            const char* sp = (t & 1) ? sbase1 : sbase0;
            s16x8 v[4];
#pragma unroll
            for (int i = 0; i < 4; ++i) v[i] = ld16_sc01(sp + i * 512);
#pragma unroll
            for (int i = 0; i < 4; ++i) {
                if (i == 0)      { WAITV(3); }
                else if (i == 1) { WAITV(2); }
                else if (i == 2) { WAITV(1); }
                else             { WAITV(0); }
                const int c = sseg + i * 32;                  // chunk 0..127
                *(s16x8*)&Hl[srow * 1024 + ((c ^ (srow & 7)) << 3)] = v[i];
            }
        }
        __syncthreads();

        // ---- 32 x (ds_read_b128 B-frag + MFMA with VGPR A=W) ----
        f32x4 acc[4];
#pragma unroll
        for (int i = 0; i < 4; ++i) acc[i] = zero4();
#pragma unroll
        for (int kb = 0; kb < 4; ++kb) {
            s16x8 h8[8];
#pragma unroll
            for (int ki = 0; ki < 8; ++ki) {
                const int cs = (kb * 8 + ki) * 4 + kg;
                h8[ki] = *(const s16x8*)&Hl[hrow * 1024 + ((cs ^ (hrow & 7)) << 3)];
            }
#pragma unroll
            for (int ki = 0; ki < 8; ++ki)
                acc[ki & 3] = __builtin_amdgcn_mfma_f32_16x16x32_bf16(
                    afr[kb * 8 + ki], h8[ki], acc[ki & 3], 0, 0, 0);
        }
        f32x4 accT = acc[0] + acc[1] + acc[2] + acc[3];

        // ---- epilogue: tanh -> ring (cvt_pk) -> drain -> flag -> states ----
        {
            float hn[4];
#pragma unroll
            for (int r = 0; r < 4; ++r)
                hn[r] = tanhf(accT[r] + ((const float*)&xw4)[r]);
            float4 st; st.x = hn[0]; st.y = hn[1]; st.z = hn[2]; st.w = hn[3];
            if (t < TT - 1) {
                if (act) {
                    u32x2 pk;
                    pk[0] = cvtpk(0.5f * (hn[0] + hprev[0]),
                                  0.5f * (hn[1] + hprev[1]));
                    pk[1] = cvtpk(0.5f * (hn[2] + hprev[2]),
                                  0.5f * (hn[3] + hprev[3]));
                    char* rw = rg + (size_t)((t + 1) & 1) * 16384;
                    st8_sc01(rw + blv * 2048 + f0 * 2, pk);
                }
                asm volatile("s_waitcnt vmcnt(0)" ::: "memory");
                __syncthreads();   // ring drained; LDS reads done
                if (tid == 0)
                    __hip_atomic_store(myflag, (unsigned)(t + 1),
                                       __ATOMIC_RELAXED, __HIP_MEMORY_SCOPE_AGENT);
                if (act) *(float4*)(out + xidx) = st;  // acks absorb in next poll
            } else {
                if (act) {
                    *(float4*)(out + xidx) = st;
                    *(float4*)(out + (size_t)BB * TT * HH + (size_t)b * HH + f0) = st;
                }
            }
#pragma unroll
            for (int r = 0; r < 4; ++r) hprev[r] = hn[r];
        }
    }
}

// ---------------------------------------------------------------------------
extern "C" void kernel_launch(void* const* d_in, const int* in_sizes, int n_in,
                              void* d_out, int out_size, void* d_ws, size_t ws_size,
                              hipStream_t stream)
{
    const float* X   = (const float*)d_in[0];
    const float* Wih = (const float*)d_in[1];
    const float* Whh = (const float*)d_in[2];
    const float* bih = (const float*)d_in[3];
    const float* bhh = (const float*)d_in[4];
    float* out = (float*)d_out;

    init_ws<<<dim3(1), dim3(256), 0, stream>>>((unsigned int*)d_ws);
    xw_gemm<<<dim3(4096), dim3(256), 0, stream>>>(X, Wih, bih, bhh, out);
    rnn_scan<<<dim3(128), dim3(256), 0, stream>>>(Whh, out, d_ws);
}